// Round 2
// 322.681 us; speedup vs baseline: 1.0249x; 1.0249x over previous
//
#include <hip/hip_runtime.h>

// FrameLogLikelihood segment-mean:
//   input  [B_SEQ*K, M] f32, B_SEQ=2048, K=2001, M=16
//   output [B_SEQ, 6*M] f32
//
// R4 theory: previous wave-per-group layout read 64B rows at 192B stride;
// every 128B line straddles two groups' rows, and nt loads evicted the line
// before the sibling wave consumed its half -> ~2x HBM fetch -> 2.4 TB/s
// plateau. This version streams fully contiguously: thread t reads v4f
// index i = t + 384*it. Row j = i>>2 advances by 96/iter and 96 % 3 == 0,
// so each thread's group residue is loop-invariant:
//   left  (j <  1000): g = (t>>2) % 3
//   right (j >  1000): g = 3 + ((t>>2)%3 + 1) % 3   (since 1001 % 3 == 2)
// Row 1000 (the overlap row) is skipped by predicate. Cross-thread
// reduction via a small LDS pass: class key = t%12 encodes (residue,quad),
// 32 contributors each, 2 regions.
//
// R5: resubmission — R4 bench was an infra failure (container died before
// running the kernel); source audited for OOB/LDS/barrier hazards: none.

constexpr int K    = 2001;
constexpr int M    = 16;
constexpr int NSEQ = 2048;
constexpr int NV   = K * 4;   // 8004 float4 per sequence
constexpr int NT   = 384;     // 6 waves; stride of 96 rows keeps j%3 fixed

typedef float v4f __attribute__((ext_vector_type(4)));

__global__ __launch_bounds__(NT) void
seg_mean_kernel(const float* __restrict__ in, float* __restrict__ out) {
    const int b = blockIdx.x;
    const int t = threadIdx.x;

    const v4f* __restrict__ base =
        reinterpret_cast<const v4f*>(in + (size_t)b * K * M);

    v4f accL = (v4f)(0.0f);   // rows 0..999,  group (t>>2)%3
    v4f accR = (v4f)(0.0f);   // rows 1001..2000, group 3+((t>>2)%3+1)%3

    // Fully contiguous streaming: block reads 384*16 B = 6 KB per iter.
    for (int i = t; i < NV; i += NT) {
        v4f v = __builtin_nontemporal_load(&base[i]);
        const int j = i >> 2;
        if (j < 1000) {
            accL += v;
        } else if (j > 1000) {
            accR += v;
        }
        // j == 1000: overlap row, dropped.
    }

    // Reduction: threads with equal key = t%12 share (residue c = key>>2,
    // quad q = key&3); rank m = t/12 in 0..31.  +1 v4f row pad kills the
    // 512B-stride bank aliasing in the second phase.
    __shared__ v4f lds[2][12][33];
    const int key = t % 12;
    const int m   = t / 12;
    lds[0][key][m] = accL;
    lds[1][key][m] = accR;
    __syncthreads();

    if (t < 24) {
        const int region = t / 12;      // 0 = left, 1 = right
        const int k2     = t % 12;
        const int c      = k2 >> 2;
        const int q      = k2 & 3;

        v4f s = (v4f)(0.0f);
#pragma unroll
        for (int mm = 0; mm < 32; ++mm) {
            s += lds[region][k2][(mm + k2) & 31];  // staggered start
        }

        const int g = (region == 0) ? c : 3 + ((c + 1) % 3);
        // counts: g0/g3 -> 334 rows, others 333
        const float cnt = (g == 0 || g == 3) ? 334.0f : 333.0f;
        v4f r = s * (1.0f / cnt);

        v4f* o = reinterpret_cast<v4f*>(out + (size_t)b * 96 + g * 16 + q * 4);
        __builtin_nontemporal_store(r, o);
    }
}

extern "C" void kernel_launch(void* const* d_in, const int* in_sizes, int n_in,
                              void* d_out, int out_size, void* d_ws, size_t ws_size,
                              hipStream_t stream) {
    const float* in = (const float*)d_in[0];
    float* out = (float*)d_out;
    seg_mean_kernel<<<NSEQ, NT, 0, stream>>>(in, out);
}